// Round 8
// baseline (2329.705 us; speedup 1.0000x reference)
//
#include <hip/hip_runtime.h>
#include <math.h>

#define H      128
#define NPATH  8192
#define TLEN   512
#define BP     32            // paths per block
#define NTHR   512           // 8 waves: (wp 0..3) x (nt 0..1)

typedef short bf16x8 __attribute__((ext_vector_type(8)));
typedef float f32x4  __attribute__((ext_vector_type(4)));

#define MFMA(a,b,c) __builtin_amdgcn_mfma_f32_16x16x32_bf16((a),(b),(c),0,0,0)
// LDS-only block barrier (validated R6: equivalent perf, correct semantics here)
#define BAR() asm volatile("s_waitcnt lgkmcnt(0)\n\ts_barrier" ::: "memory")

// ---- LDS map ----
// Weights chunk-tiled [c][row]x16B (as R5/R6)
#define O_WF2T  0                    // fwd-f A: [a>>3][n]
#define O_WG2T  32768                // fwd-g A: [a>>3][n]
#define O_WG2R  65536                // bwd   A: [b>>3][a]
// Acts chunk-tiled [c=k>>3][path]x16B
#define O_BFH   98304                // f-acts hi
#define O_BFL   106496               // f-acts lo
#define O_BGH   114688               // g-acts hi; REUSED as c2 hi in region 2
#define O_BGL   122880               // g-acts lo; c2 lo
#define O_PF    131072               // partials [4 wp][32 path] float2
#define O_PRAW  132096
#define O_PCORR 133120
#define O_EP    134144               // invariant f32 arrays [128]
#define EP_FB2   0
#define EP_GB2   512
#define EP_W3F0  1024
#define EP_W3F1  1536
#define EP_W3G0  2048
#define EP_W3G1  2560
#define EP_GW1B0 3072
#define EP_GW1B1 3584
#define EP_GB1B  4096
#define EP_FW1A  4608
#define EP_FW1B  5120
#define EP_FB1   5632
#define O_SD    140288               // silu'(z1g) f32 [32 path][132] (padded rows)
#define O_TS    157184               // ts [512] f32
#define SMEM_BYTES (O_TS + TLEN*4)   // 159232 B <= 160 KiB

__device__ __forceinline__ float bf2f(unsigned v){ return __uint_as_float(v << 16); }
__device__ __forceinline__ unsigned short f2bf(float f){
  unsigned u = __float_as_uint(f);
  return (unsigned short)((u + 0x7fffu + ((u >> 16) & 1u)) >> 16);
}
__device__ __forceinline__ float ldany(const void* p, long long i, bool isbf){
  return isbf ? bf2f(((const unsigned short*)p)[i]) : ((const float*)p)[i];
}
__device__ __forceinline__ unsigned short ldbf(const void* p, long long i, bool isbf){
  return isbf ? ((const unsigned short*)p)[i] : f2bf(((const float*)p)[i]);
}
__device__ __forceinline__ float fsig(float x){
  return __builtin_amdgcn_rcpf(1.0f + __expf(-x));
}
__device__ __forceinline__ float fsilu(float x){ return x * fsig(x); }
__device__ __forceinline__ float fsoftplus(float x){
  if (x > 15.0f) return x;
  return __logf(1.0f + __expf(x));
}
__device__ __forceinline__ unsigned cvtpk(float a, float b){
  unsigned r; asm("v_cvt_pk_bf16_f32 %0, %1, %2" : "=v"(r) : "v"(a), "v"(b)); return r;
}
__device__ __forceinline__ bf16x8 asfrag(uint4 u){
  union { uint4 u; bf16x8 b; } v; v.u = u; return v.b;
}
#define LD4(off) (*(const f32x4*)(sm + (off)))

__global__ __launch_bounds__(NTHR, 1)
void GeneratorSDE_kernel(const void* __restrict__ y0, const void* __restrict__ ts,
                         const void* __restrict__ dW,
                         const void* __restrict__ fw1, const void* __restrict__ fb1,
                         const void* __restrict__ fw2, const void* __restrict__ fb2,
                         const void* __restrict__ fw3, const void* __restrict__ fb3,
                         const void* __restrict__ gw1, const void* __restrict__ gb1,
                         const void* __restrict__ gw2, const void* __restrict__ gb2,
                         const void* __restrict__ gw3, const void* __restrict__ gb3,
                         void* __restrict__ out)
{
  extern __shared__ char sm[];
  const int tid  = threadIdx.x;
  const int lane = tid & 63;
  const int w    = tid >> 6;       // wave 0..7
  const int wp   = w >> 1;         // M-pair / b-slice index 0..3
  const int nt   = w & 1;          // half (paths nt*16..nt*16+15)
  const int m16  = lane & 15;
  const int q    = lane >> 4;      // 0..3
  const int gpb  = blockIdx.x * BP;
  const int p1   = nt*16 + m16;    // this lane's path (block-local)
  const int gp   = gpb + p1;
  const int k8   = wp*32 + q*8;    // S0 k-slice (8 neurons)

  const bool isbf = (((const unsigned*)ts)[1] != 0x3f800000u);

  // ---------- loop-invariant LDS base addresses (bytes) ----------
  const int RACTF = O_BFH + ((q*32 + p1) << 4);             // f acts: +kt*2048, +8192 lo
  const int RACTG = O_BGH + ((q*32 + p1) << 4);             // g acts: +kt*2048, +8192 lo
  const int RAF   = O_WF2T + ((q*128 + wp*32 + m16) << 4);  // f fwd A: +kt*8192, +mi*256
  const int RAG   = O_WG2T + ((q*128 + wp*32 + m16) << 4);  // g fwd A
  const int RAB   = O_WG2R + (((4*wp + q)*128 + m16) << 4); // bwd A: +mi*256 (mi 0..7)
  const int WACT  = O_BFH + (((wp*4 + q)*32 + p1) << 4);    // S0 stores: +8192/+16384/+24576
  const int WC2   = O_BGH + (((wp*4 + (q>>1))*32 + p1) << 4) + ((q&1) << 3); // +mi*1024, +8192 lo
  const int RC2   = O_BGH + (((4*wp + q)*32 + p1) << 4);    // own c2 frag, +8192 lo
  const int RPART = O_PF + (p1 << 3);
  const int WPART = O_PF + ((wp*32 + p1) << 3);
  const int REP   = O_EP + wp*128 + q*16;                   // head epilogues: +mi*64 + array
  const int REPB  = O_EP + q*16;                            // bwd epilogue:  +mi*64 + array
  const int RS0   = O_EP + (k8 << 2);                       // S0 slice reads: + array
  const int WSD   = O_SD + (p1*132 + k8)*4;                 // sd1 store (2x16B)
  const int RSD   = O_SD + (p1*132 + 4*q)*4;                // sd1 read: +mi*64

  // ---------- stage weights into LDS (chunk-tiled) ----------
  for (int e = tid; e < H * H; e += NTHR){
    int k = e >> 7, n = e & 127;   // element [a=k][b=n]
    unsigned short fv = ldbf(fw2, e, isbf);
    unsigned short gv = ldbf(gw2, e, isbf);
    *(unsigned short*)(sm + O_WF2T + (((k >> 3)*128 + n) << 4) + ((k & 7) << 1)) = fv;
    *(unsigned short*)(sm + O_WG2T + (((k >> 3)*128 + n) << 4) + ((k & 7) << 1)) = gv;
    *(unsigned short*)(sm + O_WG2R + (((n >> 3)*128 + k) << 4) + ((n & 7) << 1)) = gv;
  }
  // invariant arrays -> LDS (incl. folded layer-1 slices; frees ~48 VGPRs)
  if (tid < H){
    int e = tid;
    float r0 = ldany(fw1, e, isbf), r1 = ldany(fw1, H + e, isbf), r2 = ldany(fw1, 2*H + e, isbf);
    ((float*)(sm + O_EP + EP_FW1A))[e]  = r0 + r2;      // spread fold
    ((float*)(sm + O_EP + EP_FW1B))[e]  = r1 - r2;
    ((float*)(sm + O_EP + EP_FB1))[e]   = ldany(fb1, e, isbf);
    ((float*)(sm + O_EP + EP_FB2))[e]   = ldany(fb2, e, isbf);
    ((float*)(sm + O_EP + EP_GB2))[e]   = ldany(gb2, e, isbf);
    ((float*)(sm + O_EP + EP_W3F0))[e]  = ldany(fw3, 2*e + 0, isbf);
    ((float*)(sm + O_EP + EP_W3F1))[e]  = ldany(fw3, 2*e + 1, isbf);
    ((float*)(sm + O_EP + EP_W3G0))[e]  = ldany(gw3, 2*e + 0, isbf);
    ((float*)(sm + O_EP + EP_W3G1))[e]  = ldany(gw3, 2*e + 1, isbf);
    ((float*)(sm + O_EP + EP_GW1B0))[e] = ldany(gw1, e, isbf);
    ((float*)(sm + O_EP + EP_GW1B1))[e] = ldany(gw1, H + e, isbf);
    ((float*)(sm + O_EP + EP_GB1B))[e]  = ldany(gb1, e, isbf);
  }
  for (int e = tid; e < TLEN; e += NTHR)
    ((float*)(sm + O_TS))[e] = ldany(ts, e, isbf);

  const float fb3r0 = ldany(fb3, 0, isbf), fb3r1 = ldany(fb3, 1, isbf);
  const float gb3r0 = ldany(gb3, 0, isbf), gb3r1 = ldany(gb3, 1, isbf);

  // ---------- y in registers (redundant across the 16 lanes sharing a path) ----------
  float ycur0 = ldany(y0, (long long)gp*2 + 0, isbf);
  float ycur1 = ldany(y0, (long long)gp*2 + 1, isbf);
  if (w < 2 && lane < 16){                       // one store per path
    size_t r = (size_t)gp * TLEN;
    if (isbf) ((unsigned*)out)[r] = (unsigned)f2bf(ycur0) | ((unsigned)f2bf(ycur1) << 16);
    else      ((float2*)out)[r]   = make_float2(ycur0, ycur1);
  }
  float2 dwcur;
  {
    long long e = (long long)gp * 2;             // t = 0
    if (isbf){ unsigned u = *(const unsigned*)((const unsigned short*)dW + e);
               dwcur = make_float2(bf2f(u & 0xffffu), bf2f(u >> 16)); }
    else       dwcur = *(const float2*)((const float*)dW + e);
  }
  __syncthreads();                               // staging visible (full drain, once)

  const float* TSf = (const float*)(sm + O_TS);

  for (int t = 0; t < TLEN - 1; ++t){
    float dt = TSf[t+1] - TSf[t];
    float sqdt = sqrtf(dt);

    // prefetch next-step dW (stays in flight across BAR()s)
    float2 dwnext;
    {
      int tn = (t + 1 <= TLEN - 2) ? t + 1 : TLEN - 2;
      long long e = ((long long)tn * NPATH + gp) * 2;
      if (isbf){ unsigned u = *(const unsigned*)((const unsigned short*)dW + e);
                 dwnext = make_float2(bf2f(u & 0xffffu), bf2f(u >> 16)); }
      else       dwnext = *(const float2*)((const float*)dW + e);
    }

    // ---- S0: layer 1 for (path p1, 8 k's) + silu'(z1g) staging ----
    {
      f32x4 fav[2], fbv[2], f1v[2], ga[2], gb[2], g1[2];
      fav[0] = LD4(RS0 + EP_FW1A);  fav[1] = LD4(RS0 + EP_FW1A + 16);
      fbv[0] = LD4(RS0 + EP_FW1B);  fbv[1] = LD4(RS0 + EP_FW1B + 16);
      f1v[0] = LD4(RS0 + EP_FB1);   f1v[1] = LD4(RS0 + EP_FB1  + 16);
      ga[0]  = LD4(RS0 + EP_GW1B0); ga[1]  = LD4(RS0 + EP_GW1B0 + 16);
      gb[0]  = LD4(RS0 + EP_GW1B1); gb[1]  = LD4(RS0 + EP_GW1B1 + 16);
      g1[0]  = LD4(RS0 + EP_GB1B);  g1[1]  = LD4(RS0 + EP_GB1B  + 16);
      float hf[8], hg[8], sd[8];
      #pragma unroll
      for (int kk = 0; kk < 8; ++kk){
        int v = kk >> 2, r = kk & 3;
        float zf = f1v[v][r] + ycur0*fav[v][r] + ycur1*fbv[v][r];
        float zg = g1[v][r]  + ycur0*ga[v][r]  + ycur1*gb[v][r];
        float sf = fsig(zf); hf[kk] = zf * sf;
        float sg = fsig(zg); hg[kk] = zg * sg;
        sd[kk] = sg * (1.0f + zg * (1.0f - sg));   // silu'(z1g), reused by bwd
      }
      unsigned fh[4], fl[4], gh[4], gl[4];
      #pragma unroll
      for (int i = 0; i < 4; ++i){
        fh[i] = cvtpk(hf[2*i], hf[2*i+1]);
        gh[i] = cvtpk(hg[2*i], hg[2*i+1]);
        float f0 = __uint_as_float(fh[i] << 16), f1 = __uint_as_float(fh[i] & 0xffff0000u);
        float g0 = __uint_as_float(gh[i] << 16), g1_ = __uint_as_float(gh[i] & 0xffff0000u);
        fl[i] = cvtpk(hf[2*i] - f0, hf[2*i+1] - f1);
        gl[i] = cvtpk(hg[2*i] - g0, hg[2*i+1] - g1_);
      }
      *(uint4*)(sm + WACT        ) = make_uint4(fh[0], fh[1], fh[2], fh[3]);
      *(uint4*)(sm + WACT +  8192) = make_uint4(fl[0], fl[1], fl[2], fl[3]);
      *(uint4*)(sm + WACT + 16384) = make_uint4(gh[0], gh[1], gh[2], gh[3]);
      *(uint4*)(sm + WACT + 24576) = make_uint4(gl[0], gl[1], gl[2], gl[3]);
      *(f32x4*)(sm + WSD         ) = (f32x4){sd[0], sd[1], sd[2], sd[3]};
      *(f32x4*)(sm + WSD + 16    ) = (f32x4){sd[4], sd[5], sd[6], sd[7]};
    }
    BAR();                                               // A: acts + sd1 ready

    // ---- R1: g-fwd MFMAs + g-head partials ----
    f32x4 accg[2];
    float sgr[8];
    {
      accg[0] = (f32x4)0.f; accg[1] = (f32x4)0.f;
      #pragma unroll
      for (int kt = 0; kt < 4; ++kt){
        bf16x8 bgh = asfrag(*(const uint4*)(sm + RACTG + kt*2048       ));
        bf16x8 bgl = asfrag(*(const uint4*)(sm + RACTG + kt*2048 + 8192));
        bf16x8 ag0 = asfrag(*(const uint4*)(sm + RAG + kt*8192      ));
        bf16x8 ag1 = asfrag(*(const uint4*)(sm + RAG + kt*8192 + 256));
        accg[0] = MFMA(ag0, bgl, accg[0]); accg[0] = MFMA(ag0, bgh, accg[0]);
        accg[1] = MFMA(ag1, bgl, accg[1]); accg[1] = MFMA(ag1, bgh, accg[1]);
      }
      float pr0 = 0, pr1 = 0;
      #pragma unroll
      for (int mi = 0; mi < 2; ++mi){
        f32x4 gb2v  = LD4(REP + mi*64 + EP_GB2);
        f32x4 w3g0v = LD4(REP + mi*64 + EP_W3G0);
        f32x4 w3g1v = LD4(REP + mi*64 + EP_W3G1);
        #pragma unroll
        for (int r = 0; r < 4; ++r){
          float zg = accg[mi][r] + gb2v[r];
          float s  = fsig(zg);
          accg[mi][r] = zg;                    // biased z2g kept for c2
          sgr[mi*4+r] = s;
          float vg = zg * s;
          pr0 += vg * w3g0v[r];
          pr1 += vg * w3g1v[r];
        }
      }
      pr0 += __shfl_xor(pr0, 16, 64); pr0 += __shfl_xor(pr0, 32, 64);
      pr1 += __shfl_xor(pr1, 16, 64); pr1 += __shfl_xor(pr1, 32, 64);
      if (lane < 16)
        *(float2*)(sm + WPART + 1024) = make_float2(pr0, pr1);
    }
    BAR();                                               // B: g-partials ready

    // ---- R2: f-chain (independent) interleaved with g-tail + wave-local bwd ----
    float g0s, g1s, dw0, dw1;
    {
      // g-head combine
      float raw0 = gb3r0, raw1 = gb3r1;
      #pragma unroll
      for (int w2 = 0; w2 < 4; ++w2){
        float2 v = *(const float2*)(sm + RPART + w2*256 + 1024);
        raw0 += v.x; raw1 += v.y;
      }
      // f-fwd MFMAs (independent of g chain -> hides softplus latency)
      f32x4 accf[2];
      accf[0] = (f32x4)0.f; accf[1] = (f32x4)0.f;
      #pragma unroll
      for (int kt = 0; kt < 4; ++kt){
        bf16x8 bfh = asfrag(*(const uint4*)(sm + RACTF + kt*2048       ));
        bf16x8 bfl = asfrag(*(const uint4*)(sm + RACTF + kt*2048 + 8192));
        bf16x8 af0 = asfrag(*(const uint4*)(sm + RAF + kt*8192      ));
        bf16x8 af1 = asfrag(*(const uint4*)(sm + RAF + kt*8192 + 256));
        accf[0] = MFMA(af0, bfl, accf[0]); accf[0] = MFMA(af0, bfh, accf[0]);
        accf[1] = MFMA(af1, bfl, accf[1]); accf[1] = MFMA(af1, bfh, accf[1]);
      }
      // g tail: softplus -> g, cr
      dw0 = dwcur.x * sqdt; dw1 = dwcur.y * sqdt;
      float vv0 = 0.5f*(dw0*dw0 - dt), vv1 = 0.5f*(dw1*dw1 - dt);
      float sp0 = fsoftplus(raw0), sp1 = fsoftplus(raw1);
      g0s = fminf(fmaxf(sp0, 1e-4f), 5.0f);
      g1s = fminf(fmaxf(sp1, 1e-4f), 5.0f);
      float m0 = (sp0 > 1e-4f && sp0 < 5.0f) ? 1.0f : 0.0f;
      float m1 = (sp1 > 1e-4f && sp1 < 5.0f) ? 1.0f : 0.0f;
      float cr0 = vv0 * (g0s * fsig(raw0) * m0);
      float cr1 = vv1 * (g1s * fsig(raw1) * m1);
      // c2 -> LDS (reusing dead g-act buffers; consumed only by THIS wave)
      #pragma unroll
      for (int mi = 0; mi < 2; ++mi){
        f32x4 w3g0v = LD4(REP + mi*64 + EP_W3G0);
        f32x4 w3g1v = LD4(REP + mi*64 + EP_W3G1);
        float c2[4];
        #pragma unroll
        for (int r = 0; r < 4; ++r){
          float s = sgr[mi*4+r], z = accg[mi][r];
          float sd2 = s * (1.0f + z * (1.0f - s));
          c2[r] = (cr0 * w3g0v[r] + cr1 * w3g1v[r]) * sd2;
        }
        unsigned h0 = cvtpk(c2[0], c2[1]), h1 = cvtpk(c2[2], c2[3]);
        float a0 = __uint_as_float(h0 << 16), a1 = __uint_as_float(h0 & 0xffff0000u);
        float a2 = __uint_as_float(h1 << 16), a3 = __uint_as_float(h1 & 0xffff0000u);
        unsigned l0 = cvtpk(c2[0] - a0, c2[1] - a1), l1 = cvtpk(c2[2] - a2, c2[3] - a3);
        *(uint2*)(sm + WC2 + mi*1024       ) = make_uint2(h0, h1);
        *(uint2*)(sm + WC2 + mi*1024 + 8192) = make_uint2(l0, l1);
      }
      // f-head epilogue + PF write
      {
        float pf0 = 0, pf1 = 0;
        #pragma unroll
        for (int mi = 0; mi < 2; ++mi){
          f32x4 fb2v  = LD4(REP + mi*64 + EP_FB2);
          f32x4 w3f0v = LD4(REP + mi*64 + EP_W3F0);
          f32x4 w3f1v = LD4(REP + mi*64 + EP_W3F1);
          #pragma unroll
          for (int r = 0; r < 4; ++r){
            float vf = fsilu(accf[mi][r] + fb2v[r]);
            pf0 += vf * w3f0v[r];
            pf1 += vf * w3f1v[r];
          }
        }
        pf0 += __shfl_xor(pf0, 16, 64); pf0 += __shfl_xor(pf0, 32, 64);
        pf1 += __shfl_xor(pf1, 16, 64); pf1 += __shfl_xor(pf1, 32, 64);
        if (lane < 16)
          *(float2*)(sm + WPART) = make_float2(pf0, pf1);
      }
      // wave-local c2 visibility (same-wave write->read; no barrier)
      asm volatile("s_waitcnt lgkmcnt(0)" ::: "memory");
      // bwd: partial c1 over b-slice [32wp,32wp+32) for ALL 128 a-rows
      bf16x8 ch = asfrag(*(const uint4*)(sm + RC2       ));
      bf16x8 cl = asfrag(*(const uint4*)(sm + RC2 + 8192));
      float pc0 = 0, pc1 = 0;
      #pragma unroll
      for (int mi = 0; mi < 8; ++mi){
        bf16x8 a = asfrag(*(const uint4*)(sm + RAB + mi*256));
        f32x4 accc = (f32x4)0.f;
        accc = MFMA(a, cl, accc);
        accc = MFMA(a, ch, accc);
        f32x4 sdv = LD4(RSD  + mi*64);
        f32x4 b0v = LD4(REPB + mi*64 + EP_GW1B0);
        f32x4 b1v = LD4(REPB + mi*64 + EP_GW1B1);
        #pragma unroll
        for (int r = 0; r < 4; ++r){
          float u = accc[r] * sdv[r];          // partial-c1 * silu'(z1)
          pc0 += u * b0v[r];
          pc1 += u * b1v[r];
        }
      }
      pc0 += __shfl_xor(pc0, 16, 64); pc0 += __shfl_xor(pc0, 32, 64);
      pc1 += __shfl_xor(pc1, 16, 64); pc1 += __shfl_xor(pc1, 32, 64);
      if (lane < 16)
        *(float2*)(sm + WPART + 2048) = make_float2(pc0, pc1);
    }
    BAR();                                               // E: pf + pcorr ready

    // ---- S5: Milstein update (redundant per lane) + output ----
    {
      float f0 = fb3r0, f1 = fb3r1, c0 = 0.f, c1 = 0.f;
      #pragma unroll
      for (int w2 = 0; w2 < 4; ++w2){
        float2 a = *(const float2*)(sm + RPART + w2*256       );
        float2 b = *(const float2*)(sm + RPART + w2*256 + 2048);
        f0 += a.x; f1 += a.y; c0 += b.x; c1 += b.y;
      }
      ycur0 += f0*dt + g0s*dw0 + c0;
      ycur1 += f1*dt + g1s*dw1 + c1;
      if (w < 2 && lane < 16){
        size_t r = (size_t)gp * TLEN + (t + 1);
        if (isbf) ((unsigned*)out)[r] = (unsigned)f2bf(ycur0) | ((unsigned)f2bf(ycur1) << 16);
        else      ((float2*)out)[r]   = make_float2(ycur0, ycur1);
      }
      dwcur = dwnext;
    }
  }
}

extern "C" void kernel_launch(void* const* d_in, const int* in_sizes, int n_in,
                              void* d_out, int out_size, void* d_ws, size_t ws_size,
                              hipStream_t stream)
{
  (void)in_sizes; (void)n_in; (void)out_size; (void)d_ws; (void)ws_size;
  hipFuncSetAttribute((const void*)GeneratorSDE_kernel,
                      hipFuncAttributeMaxDynamicSharedMemorySize, SMEM_BYTES);
  GeneratorSDE_kernel<<<dim3(NPATH / BP), dim3(NTHR), SMEM_BYTES, stream>>>(
      d_in[0], d_in[1], d_in[2],
      d_in[3], d_in[4], d_in[5], d_in[6], d_in[7], d_in[8],
      d_in[9], d_in[10], d_in[11], d_in[12], d_in[13], d_in[14],
      d_out);
}